// Round 2
// baseline (465.405 us; speedup 1.0000x reference)
//
#include <hip/hip_runtime.h>
#include <cstdint>

#define S5 512
#define PLANE ((size_t)S5 * S5)   // 262144 elements per channel plane

typedef __attribute__((ext_vector_type(4))) float f32x4;
typedef __attribute__((ext_vector_type(8))) short bf16x8;

__device__ __forceinline__ unsigned short f2bf(float f) {
  union { float f; unsigned u; } v; v.f = f;
  unsigned r = v.u + 0x7fffu + ((v.u >> 16) & 1u);
  return (unsigned short)(r >> 16);
}
__device__ __forceinline__ unsigned pack2(float a, float b) {
  return (unsigned)f2bf(a) | ((unsigned)f2bf(b) << 16);
}
__device__ __forceinline__ float bf2f(unsigned short h) {
  union { unsigned u; float f; } v; v.u = ((unsigned)h) << 16;
  return v.f;
}

// ---------------------------------------------------------------- K0: weights
// wTab[256][128]: rows 0-127 = Wa^T (wTab[c][z] = Wa[z][c]), rows 128-255 = Wb^T
// wgT[128][128]:  wgT[y][z]  = Wg[z][y]
// woutT[128][128]: woutT[zo][c] = Wout[c][zo]
__global__ void k0_prep(const float* __restrict__ Wa, const float* __restrict__ Wb,
                        const float* __restrict__ Wg, const float* __restrict__ Wout,
                        unsigned short* __restrict__ wTab, unsigned short* __restrict__ wgT,
                        unsigned short* __restrict__ woutT) {
  int t = blockIdx.x * 256 + threadIdx.x;  // 0..65535
  if (t < 32768) {
    int cg = t >> 7, zz = t & 127;
    const float* W = (cg < 128) ? Wa : Wb;
    int c = cg & 127;
    wTab[t] = f2bf(W[zz * 128 + c]);
  } else if (t < 49152) {
    int u = t - 32768; int y = u >> 7, zz = u & 127;
    wgT[u] = f2bf(Wg[zz * 128 + y]);
  } else if (t < 65536) {
    int u = t - 49152; int zo = u >> 7, c = u & 127;
    woutT[u] = f2bf(Wout[c * 128 + zo]);
  }
}

// ------------------------------------------------- K1: LN(z) + a/b projection
// 64 z-rows per block, 256 cols (a|b). Weights live as register B-fragments.
// Epilogue writes channel-planes aT[c][ik], bT[c][ik] (bf16, packed 8B stores).
__launch_bounds__(256, 2)
__global__ void k1_ln_proj(const float* __restrict__ z,
                           const float* __restrict__ ln_w, const float* __restrict__ ln_b,
                           const float* __restrict__ ba, const float* __restrict__ bb,
                           const unsigned short* __restrict__ wTab,
                           unsigned short* __restrict__ aT, unsigned short* __restrict__ bT) {
  __shared__ unsigned short zs[64][136];   // pad: stride 68 dw === 4 mod 32 -> conflict-free b128
  __shared__ float lnw[128], lnb[128];
  int t = threadIdx.x;
  int lane = t & 63, w = t >> 6;
  int row0 = blockIdx.x * 64;

  if (t < 128) lnw[t] = ln_w[t];
  else lnb[t - 128] = ln_b[t - 128];

  // weight B-fragments: wave w owns global col-tiles w*4 .. w*4+3
  bf16x8 wf[4][4];
#pragma unroll
  for (int tt = 0; tt < 4; ++tt) {
    int gct = w * 4 + tt;
    int wr = gct * 16 + (lane & 15);
#pragma unroll
    for (int kk = 0; kk < 4; ++kk)
      wf[tt][kk] = *reinterpret_cast<const bf16x8*>(wTab + wr * 128 + kk * 32 + ((lane >> 4) << 3));
  }
  __syncthreads();  // lnw/lnb ready

  // LayerNorm: 4 threads per row (32 ch each), shuffle-reduce within 4-lane group
  {
    int r = t >> 2, q = t & 3;
    const float* zp = z + (size_t)(row0 + r) * 128 + q * 32;
    float v[32]; float s = 0.f, s2 = 0.f;
#pragma unroll
    for (int i = 0; i < 8; ++i) {
      f32x4 x = *reinterpret_cast<const f32x4*>(zp + i * 4);
      v[i * 4] = x[0]; v[i * 4 + 1] = x[1]; v[i * 4 + 2] = x[2]; v[i * 4 + 3] = x[3];
      s  += x[0] + x[1] + x[2] + x[3];
      s2 += x[0] * x[0] + x[1] * x[1] + x[2] * x[2] + x[3] * x[3];
    }
    s  += __shfl_xor(s, 1);  s  += __shfl_xor(s, 2);
    s2 += __shfl_xor(s2, 1); s2 += __shfl_xor(s2, 2);
    float mu = s * (1.f / 128.f);
    float var = s2 * (1.f / 128.f) - mu * mu;
    float rstd = rsqrtf(var + 1e-5f);
    unsigned pk[16];
#pragma unroll
    for (int i = 0; i < 16; ++i) {
      int c = q * 32 + i * 2;
      float a0 = (v[i * 2] - mu) * rstd * lnw[c] + lnb[c];
      float a1 = (v[i * 2 + 1] - mu) * rstd * lnw[c + 1] + lnb[c + 1];
      pk[i] = pack2(a0, a1);
    }
#pragma unroll
    for (int i = 0; i < 4; ++i)
      *reinterpret_cast<uint4*>(&zs[r][q * 32 + i * 8]) =
          make_uint4(pk[i * 4], pk[i * 4 + 1], pk[i * 4 + 2], pk[i * 4 + 3]);
  }
  __syncthreads();

  f32x4 acc[4][4];
#pragma unroll
  for (int a = 0; a < 4; ++a)
#pragma unroll
    for (int b2 = 0; b2 < 4; ++b2) { f32x4 zv = {0.f, 0.f, 0.f, 0.f}; acc[a][b2] = zv; }

#pragma unroll
  for (int kk = 0; kk < 4; ++kk) {
    bf16x8 af[4];
#pragma unroll
    for (int rt = 0; rt < 4; ++rt)
      af[rt] = *reinterpret_cast<const bf16x8*>(&zs[rt * 16 + (lane & 15)][kk * 32 + ((lane >> 4) << 3)]);
#pragma unroll
    for (int rt = 0; rt < 4; ++rt)
#pragma unroll
      for (int tt = 0; tt < 4; ++tt)
        acc[rt][tt] = __builtin_amdgcn_mfma_f32_16x16x32_bf16(af[rt], wf[tt][kk], acc[rt][tt], 0, 0, 0);
  }

  // epilogue: transposed channel-plane stores
#pragma unroll
  for (int tt = 0; tt < 4; ++tt) {
    int gct = w * 4 + tt;
    int m = gct >> 3;
    int c = ((gct & 7) << 4) + (lane & 15);
    float bias = (m ? bb : ba)[c];
    unsigned short* plane = (m ? bT : aT) + (size_t)c * PLANE;
#pragma unroll
    for (int rt = 0; rt < 4; ++rt) {
      int ik = row0 + rt * 16 + ((lane >> 4) << 2);
      f32x4 v = acc[rt][tt];
      uint2 st = make_uint2(pack2(v[0] + bias, v[1] + bias), pack2(v[2] + bias, v[3] + bias));
      *reinterpret_cast<uint2*>(plane + ik) = st;
    }
  }
}

// --------------------------------------------- K2: 128 per-channel GEMM-BT
// ab[i,j,c] = sum_k a[i,k,c] b[j,k,c]; per channel: C = A * B^T, 128x128 tile, BK=64
__launch_bounds__(256, 2)
__global__ void k2_gemm(const unsigned short* __restrict__ aT,
                        const unsigned short* __restrict__ bT,
                        unsigned short* __restrict__ abT) {
  __shared__ unsigned short As[128][72];   // stride 36 dw === 4 mod 32 -> conflict-free b128
  __shared__ unsigned short Bs[128][72];
  int t = threadIdx.x, lane = t & 63, w = t >> 6;
  int c = blockIdx.x >> 4;
  int tid = blockIdx.x & 15;
  int i0 = (tid >> 2) * 128, j0 = (tid & 3) * 128;
  const unsigned short* Ap = aT + (size_t)c * PLANE;
  const unsigned short* Bp = bT + (size_t)c * PLANE;
  int rw = (w >> 1) * 64, cw = (w & 1) * 64;

  f32x4 acc[4][4];
#pragma unroll
  for (int a = 0; a < 4; ++a)
#pragma unroll
    for (int b2 = 0; b2 < 4; ++b2) { f32x4 zv = {0.f, 0.f, 0.f, 0.f}; acc[a][b2] = zv; }

  int sr = t >> 3;          // staging row within 32-row group
  int sc = (t & 7) * 8;     // staging col (elements)
  for (int k0 = 0; k0 < 512; k0 += 64) {
#pragma unroll
    for (int p = 0; p < 4; ++p) {
      int r = p * 32 + sr;
      *reinterpret_cast<uint4*>(&As[r][sc]) =
          *reinterpret_cast<const uint4*>(Ap + (size_t)(i0 + r) * 512 + k0 + sc);
      *reinterpret_cast<uint4*>(&Bs[r][sc]) =
          *reinterpret_cast<const uint4*>(Bp + (size_t)(j0 + r) * 512 + k0 + sc);
    }
    __syncthreads();
#pragma unroll
    for (int kk = 0; kk < 2; ++kk) {
      bf16x8 af[4], bfr[4];
#pragma unroll
      for (int rt = 0; rt < 4; ++rt)
        af[rt] = *reinterpret_cast<const bf16x8*>(&As[rw + rt * 16 + (lane & 15)][kk * 32 + ((lane >> 4) << 3)]);
#pragma unroll
      for (int ct = 0; ct < 4; ++ct)
        bfr[ct] = *reinterpret_cast<const bf16x8*>(&Bs[cw + ct * 16 + (lane & 15)][kk * 32 + ((lane >> 4) << 3)]);
#pragma unroll
      for (int rt = 0; rt < 4; ++rt)
#pragma unroll
        for (int ct = 0; ct < 4; ++ct)
          acc[rt][ct] = __builtin_amdgcn_mfma_f32_16x16x32_bf16(af[rt], bfr[ct], acc[rt][ct], 0, 0, 0);
    }
    __syncthreads();
  }

  unsigned short* Op = abT + (size_t)c * PLANE;
#pragma unroll
  for (int rt = 0; rt < 4; ++rt)
#pragma unroll
    for (int ct = 0; ct < 4; ++ct) {
      int j = j0 + cw + ct * 16 + (lane & 15);
      int ib = i0 + rw + rt * 16 + ((lane >> 4) << 2);
      f32x4 v = acc[rt][ct];
#pragma unroll
      for (int rr = 0; rr < 4; ++rr)
        Op[(size_t)(ib + rr) * 512 + j] = f2bf(v[rr]);
    }
}

// ------------------- K3: gather abT, LN(ab), x WoutT; LN(z), x WgT, sigmoid; gate
// block = 64 positions (2 i-rows x 32 j), 4 waves x 16 pos each
__launch_bounds__(256, 2)
__global__ void k3_final(const float* __restrict__ z,
                         const unsigned short* __restrict__ abT,
                         const unsigned short* __restrict__ wgT,
                         const unsigned short* __restrict__ woutT,
                         const float* __restrict__ ln_w, const float* __restrict__ ln_b,
                         const float* __restrict__ lno_w, const float* __restrict__ lno_b,
                         const float* __restrict__ bg, const float* __restrict__ bout,
                         float* __restrict__ out) {
  __shared__ unsigned short Xab[64][136];
  __shared__ unsigned short Xz[64][136];
  __shared__ unsigned short wS[128][136];
  __shared__ float cvec[6 * 128];  // ln_w | ln_b | lno_w | lno_b | bg | bout
  int t = threadIdx.x, lane = t & 63, w = t >> 6;
  int i0 = (blockIdx.x >> 4) * 2;
  int j0 = (blockIdx.x & 15) * 32;

  for (int i = t; i < 768; i += 256) {
    int which = i >> 7, idx = i & 127; float vv;
    if      (which == 0) vv = ln_w[idx];
    else if (which == 1) vv = ln_b[idx];
    else if (which == 2) vv = lno_w[idx];
    else if (which == 3) vv = lno_b[idx];
    else if (which == 4) vv = bg[idx];
    else                 vv = bout[idx];
    cvec[i] = vv;
  }
  __syncthreads();

  // z LayerNorm -> Xz (bf16)
  {
    int p = t >> 2, q = t & 3;
    int li = p >> 5, jj = p & 31;
    size_t grow = (size_t)(i0 + li) * 512 + (j0 + jj);
    const float* zp = z + grow * 128 + q * 32;
    float v[32]; float s = 0.f, s2 = 0.f;
#pragma unroll
    for (int i = 0; i < 8; ++i) {
      f32x4 x = *reinterpret_cast<const f32x4*>(zp + i * 4);
      v[i * 4] = x[0]; v[i * 4 + 1] = x[1]; v[i * 4 + 2] = x[2]; v[i * 4 + 3] = x[3];
      s  += x[0] + x[1] + x[2] + x[3];
      s2 += x[0] * x[0] + x[1] * x[1] + x[2] * x[2] + x[3] * x[3];
    }
    s  += __shfl_xor(s, 1);  s  += __shfl_xor(s, 2);
    s2 += __shfl_xor(s2, 1); s2 += __shfl_xor(s2, 2);
    float mu = s * (1.f / 128.f);
    float var = s2 * (1.f / 128.f) - mu * mu;
    float rstd = rsqrtf(var + 1e-5f);
    unsigned pk[16];
#pragma unroll
    for (int i = 0; i < 16; ++i) {
      int cc = q * 32 + i * 2;
      pk[i] = pack2((v[i * 2] - mu) * rstd * cvec[cc] + cvec[128 + cc],
                    (v[i * 2 + 1] - mu) * rstd * cvec[cc + 1] + cvec[128 + cc + 1]);
    }
#pragma unroll
    for (int i = 0; i < 4; ++i)
      *reinterpret_cast<uint4*>(&Xz[p][q * 32 + i * 8]) =
          make_uint4(pk[i * 4], pk[i * 4 + 1], pk[i * 4 + 2], pk[i * 4 + 3]);
  }

  // gather abT -> Xab (transpose scatter: thread owns (channel c, i-row li))
  {
    int c = t >> 1, li = t & 1;
    const unsigned short* src = abT + (size_t)c * PLANE + (size_t)(i0 + li) * 512 + j0;
#pragma unroll
    for (int s4 = 0; s4 < 4; ++s4) {
      uint4 dv = *reinterpret_cast<const uint4*>(src + s4 * 8);
      unsigned uu[4] = {dv.x, dv.y, dv.z, dv.w};
#pragma unroll
      for (int e = 0; e < 4; ++e) {
        Xab[li * 32 + s4 * 8 + e * 2    ][c] = (unsigned short)(uu[e] & 0xffffu);
        Xab[li * 32 + s4 * 8 + e * 2 + 1][c] = (unsigned short)(uu[e] >> 16);
      }
    }
  }

  // stage WgT into wS
  {
    int r = t >> 1, h = (t & 1) * 64;
#pragma unroll
    for (int s4 = 0; s4 < 8; ++s4)
      *reinterpret_cast<uint4*>(&wS[r][h + s4 * 8]) =
          *reinterpret_cast<const uint4*>(wgT + r * 128 + h + s4 * 8);
  }
  __syncthreads();

  // LayerNorm of ab rows, in place in Xab
  {
    int p = t >> 2, q = t & 3;
    float v[32]; float s = 0.f, s2 = 0.f;
#pragma unroll
    for (int i4 = 0; i4 < 4; ++i4) {
      uint4 dv = *reinterpret_cast<const uint4*>(&Xab[p][q * 32 + i4 * 8]);
      unsigned uu[4] = {dv.x, dv.y, dv.z, dv.w};
#pragma unroll
      for (int e = 0; e < 4; ++e) {
        float x0 = bf2f((unsigned short)(uu[e] & 0xffffu));
        float x1 = bf2f((unsigned short)(uu[e] >> 16));
        v[i4 * 8 + e * 2] = x0; v[i4 * 8 + e * 2 + 1] = x1;
        s += x0 + x1; s2 += x0 * x0 + x1 * x1;
      }
    }
    s  += __shfl_xor(s, 1);  s  += __shfl_xor(s, 2);
    s2 += __shfl_xor(s2, 1); s2 += __shfl_xor(s2, 2);
    float mu = s * (1.f / 128.f);
    float var = s2 * (1.f / 128.f) - mu * mu;
    float rstd = rsqrtf(var + 1e-5f);
    unsigned pk[16];
#pragma unroll
    for (int i = 0; i < 16; ++i) {
      int cc = q * 32 + i * 2;
      pk[i] = pack2((v[i * 2] - mu) * rstd * cvec[256 + cc] + cvec[384 + cc],
                    (v[i * 2 + 1] - mu) * rstd * cvec[256 + cc + 1] + cvec[384 + cc + 1]);
    }
#pragma unroll
    for (int i4 = 0; i4 < 4; ++i4)
      *reinterpret_cast<uint4*>(&Xab[p][q * 32 + i4 * 8]) =
          make_uint4(pk[i4 * 4], pk[i4 * 4 + 1], pk[i4 * 4 + 2], pk[i4 * 4 + 3]);
  }
  __syncthreads();

  // g-GEMM: gl[p][y] = Xz . WgT, then sigmoid, packed to bf16 regs
  f32x4 ga[8];
#pragma unroll
  for (int i = 0; i < 8; ++i) { f32x4 zv = {0.f, 0.f, 0.f, 0.f}; ga[i] = zv; }
#pragma unroll
  for (int kk = 0; kk < 4; ++kk) {
    bf16x8 af = *reinterpret_cast<const bf16x8*>(&Xz[w * 16 + (lane & 15)][kk * 32 + ((lane >> 4) << 3)]);
#pragma unroll
    for (int ct = 0; ct < 8; ++ct) {
      bf16x8 bfr = *reinterpret_cast<const bf16x8*>(&wS[ct * 16 + (lane & 15)][kk * 32 + ((lane >> 4) << 3)]);
      ga[ct] = __builtin_amdgcn_mfma_f32_16x16x32_bf16(af, bfr, ga[ct], 0, 0, 0);
    }
  }
  unsigned gp[8][2];
#pragma unroll
  for (int ct = 0; ct < 8; ++ct) {
    int y = ct * 16 + (lane & 15);
    float b4 = cvec[512 + y];
    float g0 = 1.f / (1.f + expf(-(ga[ct][0] + b4)));
    float g1 = 1.f / (1.f + expf(-(ga[ct][1] + b4)));
    float g2 = 1.f / (1.f + expf(-(ga[ct][2] + b4)));
    float g3 = 1.f / (1.f + expf(-(ga[ct][3] + b4)));
    gp[ct][0] = pack2(g0, g1);
    gp[ct][1] = pack2(g2, g3);
  }
  __syncthreads();  // done reading WgT

  // stage WoutT into wS
  {
    int r = t >> 1, h = (t & 1) * 64;
#pragma unroll
    for (int s4 = 0; s4 < 8; ++s4)
      *reinterpret_cast<uint4*>(&wS[r][h + s4 * 8]) =
          *reinterpret_cast<const uint4*>(woutT + r * 128 + h + s4 * 8);
  }
  __syncthreads();

  // out-GEMM: oa[p][zo] = LN(ab) . WoutT
  f32x4 oa[8];
#pragma unroll
  for (int i = 0; i < 8; ++i) { f32x4 zv = {0.f, 0.f, 0.f, 0.f}; oa[i] = zv; }
#pragma unroll
  for (int kk = 0; kk < 4; ++kk) {
    bf16x8 af = *reinterpret_cast<const bf16x8*>(&Xab[w * 16 + (lane & 15)][kk * 32 + ((lane >> 4) << 3)]);
#pragma unroll
    for (int ct = 0; ct < 8; ++ct) {
      bf16x8 bfr = *reinterpret_cast<const bf16x8*>(&wS[ct * 16 + (lane & 15)][kk * 32 + ((lane >> 4) << 3)]);
      oa[ct] = __builtin_amdgcn_mfma_f32_16x16x32_bf16(af, bfr, oa[ct], 0, 0, 0);
    }
  }

  // gate + bias + store fp32
#pragma unroll
  for (int ct = 0; ct < 8; ++ct) {
    int zc = ct * 16 + (lane & 15);
    float bo = cvec[640 + zc];
#pragma unroll
    for (int rr = 0; rr < 4; ++rr) {
      int p = w * 16 + ((lane >> 4) << 2) + rr;
      int li = p >> 5, jj = p & 31;
      size_t grow = (size_t)(i0 + li) * 512 + (j0 + jj);
      float gv = bf2f((unsigned short)(gp[ct][rr >> 1] >> ((rr & 1) * 16)));
      out[grow * 128 + zc] = gv * (oa[ct][rr] + bo);
    }
  }
}

extern "C" void kernel_launch(void* const* d_in, const int* in_sizes, int n_in,
                              void* d_out, int out_size, void* d_ws, size_t ws_size,
                              hipStream_t stream) {
  const float* z     = (const float*)d_in[0];
  const float* ln_w  = (const float*)d_in[1];
  const float* ln_b  = (const float*)d_in[2];
  const float* Wa    = (const float*)d_in[3];
  const float* ba    = (const float*)d_in[4];
  const float* Wb    = (const float*)d_in[5];
  const float* bb    = (const float*)d_in[6];
  const float* Wg    = (const float*)d_in[7];
  const float* bg    = (const float*)d_in[8];
  const float* lno_w = (const float*)d_in[9];
  const float* lno_b = (const float*)d_in[10];
  const float* Wout  = (const float*)d_in[11];
  const float* bout  = (const float*)d_in[12];
  float* out = (float*)d_out;

  char* ws = (char*)d_ws;
  unsigned short* aT    = (unsigned short*)(ws);                  // 67,108,864 B
  unsigned short* bT    = (unsigned short*)(ws + 67108864);       // 67,108,864 B
  unsigned short* abT   = (unsigned short*)(ws + 134217728);      // 67,108,864 B
  unsigned short* wTab  = (unsigned short*)(ws + 201326592);      // 65,536 B
  unsigned short* wgT   = (unsigned short*)(ws + 201392128);      // 32,768 B
  unsigned short* woutT = (unsigned short*)(ws + 201424896);      // 32,768 B

  k0_prep<<<256, 256, 0, stream>>>(Wa, Wb, Wg, Wout, wTab, wgT, woutT);
  k1_ln_proj<<<4096, 256, 0, stream>>>(z, ln_w, ln_b, ba, bb, wTab, aT, bT);
  k2_gemm<<<2048, 256, 0, stream>>>(aT, bT, abT);
  k3_final<<<4096, 256, 0, stream>>>(z, abT, wgT, woutT, ln_w, ln_b, lno_w, lno_b,
                                     bg, bout, out);
}